// Round 6
// baseline (314.165 us; speedup 1.0000x reference)
//
#include <hip/hip_runtime.h>
#include <hip/hip_bf16.h>

#define N_NODES 4096
#define E_EDGES 131072
#define DIN_    512
#define DM_     256
#define DFF_    2048
#define EPS_    1e-5f
#define NSPLIT  8

typedef __attribute__((ext_vector_type(8))) short bf16x8;   // 8 bf16 = 4 VGPR
typedef __attribute__((ext_vector_type(4))) float f32x4;

__device__ __forceinline__ short f2b(float f) {
    union { float f; unsigned u; } x; x.f = f;
    unsigned r = x.u + 0x7fff + ((x.u >> 16) & 1);   // RNE
    return (short)(r >> 16);
}

// ---------------------------------------------------------------------------
// casts
// ---------------------------------------------------------------------------
__global__ __launch_bounds__(256)
void castf2b_kernel(const float* __restrict__ s, short* __restrict__ d, int n4) {
    int i = blockIdx.x * 256 + threadIdx.x;
    if (i >= n4) return;
    float4 v = reinterpret_cast<const float4*>(s)[i];
    union { short s[4]; int2 v; } o;
    o.s[0] = f2b(v.x); o.s[1] = f2b(v.y); o.s[2] = f2b(v.z); o.s[3] = f2b(v.w);
    reinterpret_cast<int2*>(d)[i] = o.v;
}

// W_gcn [512][256] f32 -> WgT [256][512] bf16
__global__ __launch_bounds__(256)
void wgt_kernel(const float* __restrict__ W, short* __restrict__ WT) {
    __shared__ float t[32][33];
    const int tx = threadIdx.x & 31, ty = threadIdx.x >> 5;
    const int bk = blockIdx.x * 32, bn = blockIdx.y * 32;
    #pragma unroll
    for (int i = 0; i < 4; ++i) {
        int r = ty + i * 8;
        t[r][tx] = W[(size_t)(bk + r) * DM_ + bn + tx];
    }
    __syncthreads();
    #pragma unroll
    for (int i = 0; i < 4; ++i) {
        int r = ty + i * 8;
        WT[(size_t)(bn + r) * DIN_ + bk + tx] = f2b(t[tx][r]);
    }
}

// qkv bf16 [4096][768] cols 512..767 -> VT [256][4096] (row d = head*128+dh)
__global__ __launch_bounds__(256)
void vt_kernel(const short* __restrict__ qkv, short* __restrict__ VT) {
    __shared__ short t[32][33];
    const int tx = threadIdx.x & 31, ty = threadIdx.x >> 5;
    const int bn = blockIdx.x * 32, bd = blockIdx.y * 32;
    #pragma unroll
    for (int i = 0; i < 4; ++i) {
        int r = ty + i * 8;
        t[r][tx] = qkv[(size_t)(bn + r) * 768 + 512 + bd + tx];
    }
    __syncthreads();
    #pragma unroll
    for (int i = 0; i < 4; ++i) {
        int r = ty + i * 8;
        VT[(size_t)(bd + r) * N_NODES + bn + tx] = t[tx][r];
    }
}

// ---------------------------------------------------------------------------
// bf16 MFMA GEMM: C = A[M,K] @ B^T  (B given row-major [N,K]) + bias, epi.
// 128x128 tile, 4 waves (each 64x64), BK=32, A staged in LDS (XOR-swizzled
// 16B chunks), B frags read direct from global (L2-resident weights).
// ---------------------------------------------------------------------------
template<bool BF16OUT, bool RELU, bool SPLITK>
__global__ __launch_bounds__(256)
void mgemm_kernel(const short* __restrict__ A, const short* __restrict__ B,
                  const float* __restrict__ bias,
                  float* __restrict__ Cf, short* __restrict__ Cb,
                  int M, int N, int K, int lda, int ldb, int ldc, int kchunk)
{
    __shared__ short As[128 * 32];    // 8 KB
    const int tid = threadIdx.x;
    const int lane = tid & 63, w = tid >> 6;
    const int c = lane & 15, g = lane >> 4;
    const int wm = (w >> 1) * 64, wn = (w & 1) * 64;
    const int bm = blockIdx.y * 128, bn = blockIdx.x * 128;
    int k0 = 0, kend = K;
    if (SPLITK) { k0 = blockIdx.z * kchunk; kend = min(K, k0 + kchunk); }

    const int srow = tid >> 1;               // 0..127
    const int kc0  = (tid & 1) * 2;          // 16B-chunk 0 or 2
    const short* Ag = A + (size_t)(bm + srow) * lda;

    f32x4 acc[4][4] = {};
    for (int kb = k0; kb < kend; kb += 32) {
        #pragma unroll
        for (int i = 0; i < 2; ++i) {
            int kc = kc0 + i;
            bf16x8 v = *reinterpret_cast<const bf16x8*>(Ag + kb + kc * 8);
            int kcs = kc ^ ((srow >> 1) & 3);
            *reinterpret_cast<bf16x8*>(&As[srow * 32 + kcs * 8]) = v;
        }
        __syncthreads();
        bf16x8 bf[4];
        #pragma unroll
        for (int nf = 0; nf < 4; ++nf)
            bf[nf] = *reinterpret_cast<const bf16x8*>(
                B + (size_t)(bn + wn + nf * 16 + c) * ldb + kb + g * 8);
        bf16x8 af[4];
        #pragma unroll
        for (int mf = 0; mf < 4; ++mf) {
            int row = wm + mf * 16 + c;
            int kcs = g ^ ((row >> 1) & 3);
            af[mf] = *reinterpret_cast<const bf16x8*>(&As[row * 32 + kcs * 8]);
        }
        #pragma unroll
        for (int mf = 0; mf < 4; ++mf)
            #pragma unroll
            for (int nf = 0; nf < 4; ++nf)
                acc[mf][nf] = __builtin_amdgcn_mfma_f32_16x16x32_bf16(
                    af[mf], bf[nf], acc[mf][nf], 0, 0, 0);
        __syncthreads();
    }
    #pragma unroll
    for (int mf = 0; mf < 4; ++mf) {
        const int row = bm + wm + mf * 16 + g * 4;
        #pragma unroll
        for (int nf = 0; nf < 4; ++nf) {
            const int col = bn + wn + nf * 16 + c;
            float bv = bias ? bias[col] : 0.f;
            #pragma unroll
            for (int v = 0; v < 4; ++v) {
                float val = acc[mf][nf][v];
                size_t o = (size_t)(row + v) * ldc + col;
                if (SPLITK) {
                    if (blockIdx.z == 0) val += bv;
                    atomicAdd(&Cf[o], val);
                } else {
                    val += bv;
                    if (RELU) val = fmaxf(val, 0.f);
                    if (BF16OUT) Cb[o] = f2b(val);
                    else         Cf[o] = val;
                }
            }
        }
    }
}

// ---------------------------------------------------------------------------
// Flash attention, KV-split, XCD-local, defer-max softmax (log2 units).
// 1024 blocks x 256 thr (4 waves x 16 q-rows). Split = 512 keys.
// Per-tile: NO cross-lane reductions in steady state -- per-lane lsum
// accumulation + __all() deferred-max check; shfl reduce only on max growth
// (THR=8 in log2 -> P <= 256) and once in the epilogue.
// ---------------------------------------------------------------------------
__global__ __launch_bounds__(256)
void fattn_kernel(const short* __restrict__ qkv, const short* __restrict__ VT,
                  short* __restrict__ Opart, float* __restrict__ ml)
{
    const int bid = blockIdx.x;
    const int j = bid >> 3;
    const int pair = 2 * (bid & 7) + (j & 1);
    const int hd = pair >> 3, sp = pair & 7;
    const int qt = j >> 1;
    const int w = threadIdx.x >> 6, lane = threadIdx.x & 63;
    const int c = lane & 15, g = lane >> 4;
    const int q0 = qt * 64 + w * 16;
    __shared__ short Plds[4][16][88];    // padded: 176B row stride -> 2-way

    const short* Q  = qkv + (size_t)q0 * 768 + hd * 128;
    const short* Kb = qkv + 256 + hd * 128;
    const short* Vt = VT + (size_t)hd * 128 * N_NODES;

    bf16x8 qf[4];
    #pragma unroll
    for (int ks = 0; ks < 4; ++ks)
        qf[ks] = *reinterpret_cast<const bf16x8*>(Q + (size_t)c * 768 + ks * 32 + g * 8);

    f32x4 O[8] = {};
    float m[4]  = {-1e30f, -1e30f, -1e30f, -1e30f};
    float lsum[4] = {};                       // per-lane partial row sums
    const float C = 0.12751744f;              // log2(e)/sqrt(128)

    for (int kt = sp * 8; kt < sp * 8 + 8; ++kt) {
        const int key0 = kt * 64;
        f32x4 S[4] = {};
        #pragma unroll
        for (int nf = 0; nf < 4; ++nf) {
            const short* Kr = Kb + (size_t)(key0 + nf * 16 + c) * 768;
            #pragma unroll
            for (int ks = 0; ks < 4; ++ks) {
                bf16x8 kf = *reinterpret_cast<const bf16x8*>(Kr + ks * 32 + g * 8);
                S[nf] = __builtin_amdgcn_mfma_f32_16x16x32_bf16(qf[ks], kf, S[nf], 0, 0, 0);
            }
        }
        // z = scores in log2 units; row r = 4g+v, col = nf*16+c
        float z[4][4];
        float lmax[4];
        bool ok = true;
        #pragma unroll
        for (int v = 0; v < 4; ++v) {
            #pragma unroll
            for (int nf = 0; nf < 4; ++nf) z[nf][v] = S[nf][v] * C;
            lmax[v] = fmaxf(fmaxf(z[0][v], z[1][v]), fmaxf(z[2][v], z[3][v]));
            ok = ok && (lmax[v] <= m[v] + 8.f);
        }
        if (!__all(ok)) {                       // rare: max grew past bound
            float mx[4];
            #pragma unroll
            for (int v = 0; v < 4; ++v) mx[v] = lmax[v];
            #pragma unroll
            for (int off = 1; off <= 8; off <<= 1)
                #pragma unroll
                for (int v = 0; v < 4; ++v) mx[v] = fmaxf(mx[v], __shfl_xor(mx[v], off));
            #pragma unroll
            for (int v = 0; v < 4; ++v) {
                float mn = fmaxf(m[v], mx[v]);
                float scl = exp2f(m[v] - mn);
                m[v] = mn;
                lsum[v] *= scl;
                #pragma unroll
                for (int nf2 = 0; nf2 < 8; ++nf2) O[nf2][v] *= scl;
            }
        }
        #pragma unroll
        for (int nf = 0; nf < 4; ++nf)
            #pragma unroll
            for (int v = 0; v < 4; ++v) {
                float p = exp2f(z[nf][v] - m[v]);    // <= 256
                lsum[v] += p;
                union { float f; unsigned u; } pu; pu.f = p;
                Plds[w][4 * g + v][nf * 16 + c] = (short)(pu.u >> 16);  // RTZ
            }
        // PV: A-frags from Plds (same wave; compiler orders via lgkmcnt)
        bf16x8 pa[2];
        #pragma unroll
        for (int ks = 0; ks < 2; ++ks)
            pa[ks] = *reinterpret_cast<const bf16x8*>(&Plds[w][c][ks * 32 + g * 8]);
        #pragma unroll
        for (int nf2 = 0; nf2 < 8; ++nf2) {
            const short* Vr = Vt + (size_t)(nf2 * 16 + c) * N_NODES + key0;
            #pragma unroll
            for (int ks = 0; ks < 2; ++ks) {
                bf16x8 vf = *reinterpret_cast<const bf16x8*>(Vr + ks * 32 + g * 8);
                O[nf2] = __builtin_amdgcn_mfma_f32_16x16x32_bf16(pa[ks], vf, O[nf2], 0, 0, 0);
            }
        }
    }
    // epilogue: one cross-lane sum reduce for lsum
    #pragma unroll
    for (int off = 1; off <= 8; off <<= 1)
        #pragma unroll
        for (int v = 0; v < 4; ++v) lsum[v] += __shfl_xor(lsum[v], off);
    // write partials: Opart[((hd*NSPLIT+sp)*4096 + row)*128 + dh], ml[...*2]
    const size_t pbase = ((size_t)hd * NSPLIT + sp) * N_NODES;
    #pragma unroll
    for (int v = 0; v < 4; ++v) {
        const int row = q0 + 4 * g + v;
        const size_t rowo = (pbase + row) * 128;
        #pragma unroll
        for (int nf2 = 0; nf2 < 8; ++nf2)
            Opart[rowo + nf2 * 16 + c] = f2b(O[nf2][v]);
        if (c == 0) {
            ml[(pbase + row) * 2 + 0] = m[v];       // log2 units
            ml[(pbase + row) * 2 + 1] = lsum[v];
        }
    }
}

// combine NSPLIT partials -> attnb bf16 [4096][256]; grid (4096, 2), 128 thr
// (m values are in log2 units -> exp2f weights)
__global__ __launch_bounds__(128)
void attn_combine_kernel(const short* __restrict__ Opart, const float* __restrict__ ml,
                         short* __restrict__ attnb)
{
    const int row = blockIdx.x, hd = blockIdx.y, d = threadIdx.x;
    float ms[NSPLIT], ls[NSPLIT];
    float mmax = -1e30f;
    #pragma unroll
    for (int s = 0; s < NSPLIT; ++s) {
        const size_t p = ((size_t)hd * NSPLIT + s) * N_NODES + row;
        ms[s] = ml[p * 2 + 0];
        ls[s] = ml[p * 2 + 1];
        mmax = fmaxf(mmax, ms[s]);
    }
    float lt = 0.f, acc = 0.f;
    #pragma unroll
    for (int s = 0; s < NSPLIT; ++s) {
        const float wgt = exp2f(ms[s] - mmax);
        lt += wgt * ls[s];
        const size_t p = ((size_t)hd * NSPLIT + s) * N_NODES + row;
        union { short s; unsigned short u; } b; b.s = Opart[p * 128 + d];
        union { unsigned u; float f; } cv; cv.u = ((unsigned)b.u) << 16;
        acc += wgt * cv.f;
    }
    attnb[(size_t)row * DM_ + hd * 128 + d] = f2b(acc / lt);
}

// ---------------------------------------------------------------------------
// GCN: degree, CSR build, gather-aggregate
// ---------------------------------------------------------------------------
__global__ void deg_init_kernel(float* deg, int* count) {
    int i = blockIdx.x * 256 + threadIdx.x;
    if (i < N_NODES) { deg[i] = 1.0f; count[i] = 0; }
}
__global__ void deg_accum_kernel(const int* __restrict__ dst,
                                 const float* __restrict__ w,
                                 float* deg, int* count) {
    int e = blockIdx.x * 256 + threadIdx.x;
    if (e < E_EDGES) {
        int d = dst[e];
        atomicAdd(&deg[d], w[e]);
        atomicAdd(&count[d], 1);
    }
}
__global__ void dinv_kernel(float* deg) {
    int i = blockIdx.x * 256 + threadIdx.x;
    if (i < N_NODES) deg[i] = rsqrtf(deg[i]);
}
__global__ __launch_bounds__(256)
void csr_scan_kernel(const int* __restrict__ count, int* __restrict__ start,
                     int* __restrict__ cursor) {
    __shared__ int sum[256];
    const int tid = threadIdx.x;
    const int base = tid * 16;
    int loc[16]; int s = 0;
    #pragma unroll
    for (int i = 0; i < 16; ++i) { loc[i] = count[base + i]; s += loc[i]; }
    sum[tid] = s;
    __syncthreads();
    for (int off = 1; off < 256; off <<= 1) {
        int v = (tid >= off) ? sum[tid - off] : 0;
        __syncthreads();
        sum[tid] += v;
        __syncthreads();
    }
    int run = sum[tid] - s;
    #pragma unroll
    for (int i = 0; i < 16; ++i) {
        start[base + i] = run;
        cursor[base + i] = run;
        run += loc[i];
    }
    if (tid == 255) start[N_NODES] = run;
}
__global__ void csr_fill_kernel(const int* __restrict__ src, const int* __restrict__ dst,
                                const float* __restrict__ w, const float* __restrict__ dinv,
                                int* __restrict__ cursor,
                                int* __restrict__ csr_src, float* __restrict__ csr_nrm) {
    int e = blockIdx.x * 256 + threadIdx.x;
    if (e >= E_EDGES) return;
    int s = src[e], d = dst[e];
    int pos = atomicAdd(&cursor[d], 1);
    csr_src[pos] = s;
    csr_nrm[pos] = dinv[s] * w[e] * dinv[d];
}
// one block per dst node; fuses self-loop + bias + ReLU; writes f32 + bf16
__global__ __launch_bounds__(256)
void gcn_gather_kernel(const int* __restrict__ start, const int* __restrict__ csr_src,
                       const float* __restrict__ csr_nrm, const float* __restrict__ xw,
                       const float* __restrict__ dinv, const float* __restrict__ b,
                       float* __restrict__ h, short* __restrict__ hb) {
    const int n = blockIdx.x, d = threadIdx.x;
    const int s0 = start[n], s1 = start[n + 1];
    float acc = 0.f;
    __shared__ int   ssrc[256];
    __shared__ float snrm[256];
    for (int base = s0; base < s1; base += 256) {
        const int cnt = min(256, s1 - base);
        __syncthreads();
        if (d < cnt) { ssrc[d] = csr_src[base + d]; snrm[d] = csr_nrm[base + d]; }
        __syncthreads();
        for (int j = 0; j < cnt; ++j)
            acc = fmaf(snrm[j], xw[(size_t)ssrc[j] * DM_ + d], acc);
    }
    const float di = dinv[n];
    float v = acc + di * di * xw[(size_t)n * DM_ + d] + b[d];
    v = fmaxf(v, 0.f);
    h[(size_t)n * DM_ + d] = v;
    hb[(size_t)n * DM_ + d] = f2b(v);
}

// ---------------------------------------------------------------------------
// LayerNorm(a+b); writes f32 (always) and bf16 (if outb != null)
// ---------------------------------------------------------------------------
__global__ __launch_bounds__(256)
void ln_kernel(const float* __restrict__ a, const float* __restrict__ b,
               const float* __restrict__ g, const float* __restrict__ be,
               float* __restrict__ outf, short* __restrict__ outb) {
    const int n = blockIdx.x, d = threadIdx.x;
    const size_t idx = (size_t)n * DM_ + d;
    float x = a[idx] + b[idx];
    float s = x;
    #pragma unroll
    for (int off = 32; off; off >>= 1) s += __shfl_xor(s, off);
    __shared__ float red[8];
    const int wid = d >> 6;
    if ((d & 63) == 0) red[wid] = s;
    __syncthreads();
    float mu = (red[0] + red[1] + red[2] + red[3]) * (1.f / 256.f);
    float c = x - mu;
    float q = c * c;
    #pragma unroll
    for (int off = 32; off; off >>= 1) q += __shfl_xor(q, off);
    if ((d & 63) == 0) red[4 + wid] = q;
    __syncthreads();
    float var = (red[4] + red[5] + red[6] + red[7]) * (1.f / 256.f);
    float v = c * rsqrtf(var + EPS_) * g[d] + be[d];
    outf[idx] = v;
    if (outb) outb[idx] = f2b(v);
}

// ---------------------------------------------------------------------------
extern "C" void kernel_launch(void* const* d_in, const int* in_sizes, int n_in,
                              void* d_out, int out_size, void* d_ws, size_t ws_size,
                              hipStream_t stream) {
    const float* x   = (const float*)d_in[0];
    const int*   ei  = (const int*)  d_in[1];
    const float* ew  = (const float*)d_in[2];
    const float* Wg  = (const float*)d_in[3];
    const float* bg  = (const float*)d_in[4];
    const float* inw = (const float*)d_in[5];
    const float* inb = (const float*)d_in[6];
    const float* ow  = (const float*)d_in[7];
    const float* ob  = (const float*)d_in[8];
    const float* l1w = (const float*)d_in[9];
    const float* l1b = (const float*)d_in[10];
    const float* l2w = (const float*)d_in[11];
    const float* l2b = (const float*)d_in[12];
    const float* g1  = (const float*)d_in[13];
    const float* b1  = (const float*)d_in[14];
    const float* g2  = (const float*)d_in[15];
    const float* b2  = (const float*)d_in[16];
    float* out = (float*)d_out;

    char* ws = (char*)d_ws;
    size_t off = 0;
    auto alloc = [&](size_t bytes) {
        void* p = ws + off;
        off += (bytes + 255) & ~(size_t)255;
        return p;
    };
    float* deg     = (float*)alloc((size_t)N_NODES * 4);
    int*   count   = (int*)  alloc((size_t)N_NODES * 4);
    int*   startA  = (int*)  alloc((size_t)(N_NODES + 1) * 4);
    int*   cursor  = (int*)  alloc((size_t)N_NODES * 4);
    int*   csr_src = (int*)  alloc((size_t)E_EDGES * 4);
    float* csr_nrm = (float*)alloc((size_t)E_EDGES * 4);
    short* xb    = (short*)alloc((size_t)N_NODES * DIN_ * 2);          // 4 MB
    short* WgT   = (short*)alloc((size_t)DM_ * DIN_ * 2);
    short* inwb  = (short*)alloc((size_t)768 * DM_ * 2);
    short* owb   = (short*)alloc((size_t)DM_ * DM_ * 2);
    short* l1wb  = (short*)alloc((size_t)DFF_ * DM_ * 2);
    short* l2wb  = (short*)alloc((size_t)DM_ * DFF_ * 2);
    float* xw    = (float*)alloc((size_t)N_NODES * DM_ * 4);           // 4 MB
    float* h     = (float*)alloc((size_t)N_NODES * DM_ * 4);
    short* hb    = (short*)alloc((size_t)N_NODES * DM_ * 2);
    short* qkvb  = (short*)alloc((size_t)N_NODES * 768 * 2);           // 6 MB
    short* VT    = (short*)alloc((size_t)DM_ * N_NODES * 2);           // 2 MB
    short* attnb = (short*)alloc((size_t)N_NODES * DM_ * 2);
    float* tmp   = (float*)alloc((size_t)N_NODES * DM_ * 4);
    float* h1    = (float*)alloc((size_t)N_NODES * DM_ * 4);
    short* h1b   = (short*)alloc((size_t)N_NODES * DM_ * 2);
    // shared region: {Opart bf16 + ml f32} during attention, ff1b during FFN
    size_t opart_b = (size_t)2 * NSPLIT * N_NODES * 128 * 2;           // 16.8 MB
    size_t ml_b    = (size_t)2 * NSPLIT * N_NODES * 2 * 4;             // 0.5 MB
    size_t ff1_b   = (size_t)N_NODES * DFF_ * 2;                       // 16 MB
    char*  R     = (char*)alloc(opart_b + ml_b > ff1_b ? opart_b + ml_b : ff1_b);
    short* Opart = (short*)R;
    float* ml    = (float*)(R + opart_b);
    short* ff1b  = (short*)R;
    (void)ws_size; (void)in_sizes; (void)n_in; (void)out_size;

    const int* srcI = ei;
    const int* dstI = ei + E_EDGES;

    // ---- casts ----
    castf2b_kernel<<<2048, 256, 0, stream>>>(x, xb, N_NODES * DIN_ / 4);
    wgt_kernel<<<dim3(16, 8), 256, 0, stream>>>(Wg, WgT);
    castf2b_kernel<<<192, 256, 0, stream>>>(inw, inwb, 768 * DM_ / 4);
    castf2b_kernel<<<64, 256, 0, stream>>>(ow, owb, DM_ * DM_ / 4);
    castf2b_kernel<<<512, 256, 0, stream>>>(l1w, l1wb, DFF_ * DM_ / 4);
    castf2b_kernel<<<512, 256, 0, stream>>>(l2w, l2wb, DM_ * DFF_ / 4);

    // ---- GCN ----
    deg_init_kernel<<<16, 256, 0, stream>>>(deg, count);
    deg_accum_kernel<<<E_EDGES / 256, 256, 0, stream>>>(dstI, ew, deg, count);
    dinv_kernel<<<16, 256, 0, stream>>>(deg);
    csr_scan_kernel<<<1, 256, 0, stream>>>(count, startA, cursor);
    csr_fill_kernel<<<E_EDGES / 256, 256, 0, stream>>>(srcI, dstI, ew, deg, cursor,
                                                       csr_src, csr_nrm);
    mgemm_kernel<false, false, false><<<dim3(2, 32), 256, 0, stream>>>(
        xb, WgT, nullptr, xw, nullptr, N_NODES, DM_, DIN_, DIN_, DIN_, DM_, 0);
    gcn_gather_kernel<<<N_NODES, 256, 0, stream>>>(startA, csr_src, csr_nrm, xw,
                                                   deg, bg, h, hb);

    // ---- QKV ----
    mgemm_kernel<true, false, false><<<dim3(6, 32), 256, 0, stream>>>(
        hb, inwb, inb, nullptr, qkvb, N_NODES, 768, DM_, DM_, DM_, 768, 0);
    vt_kernel<<<dim3(128, 8), 256, 0, stream>>>(qkvb, VT);

    // ---- flash attention (KV-split, XCD-local, defer-max) + combine ----
    fattn_kernel<<<1024, 256, 0, stream>>>(qkvb, VT, Opart, ml);
    attn_combine_kernel<<<dim3(N_NODES, 2), 128, 0, stream>>>(Opart, ml, attnb);

    // ---- out_proj + LN1 ----
    mgemm_kernel<false, false, false><<<dim3(2, 32), 256, 0, stream>>>(
        attnb, owb, ob, tmp, nullptr, N_NODES, DM_, DM_, DM_, DM_, DM_, 0);
    ln_kernel<<<N_NODES, 256, 0, stream>>>(h, tmp, g1, b1, h1, h1b);

    // ---- FFN ----
    mgemm_kernel<true, true, false><<<dim3(16, 32), 256, 0, stream>>>(
        h1b, l1wb, l1b, nullptr, ff1b, N_NODES, DFF_, DM_, DM_, DM_, DFF_, 0);
    hipMemsetAsync(tmp, 0, (size_t)N_NODES * DM_ * 4, stream);
    mgemm_kernel<false, false, true><<<dim3(2, 32, 4), 256, 0, stream>>>(
        ff1b, l2wb, l2b, tmp, nullptr, N_NODES, DM_, DFF_, DFF_, DFF_, DM_, 512);
    ln_kernel<<<N_NODES, 256, 0, stream>>>(h1, tmp, g2, b2, out, nullptr);
}

// Round 7
// 240.394 us; speedup vs baseline: 1.3069x; 1.3069x over previous
//
#include <hip/hip_runtime.h>
#include <hip/hip_bf16.h>

#define N_NODES 4096
#define E_EDGES 131072
#define DIN_    512
#define DM_     256
#define DFF_    2048
#define EPS_    1e-5f
#define NSPLIT  8

typedef __attribute__((ext_vector_type(8))) short bf16x8;   // 8 bf16 = 4 VGPR
typedef __attribute__((ext_vector_type(4))) float f32x4;

__device__ __forceinline__ short f2b(float f) {
    union { float f; unsigned u; } x; x.f = f;
    unsigned r = x.u + 0x7fff + ((x.u >> 16) & 1);   // RNE
    return (short)(r >> 16);
}

// async global->LDS, 16B per lane; lptr must be wave-uniform (HW adds lane*16)
__device__ __forceinline__ void gload16(const void* g, void* l) {
    __builtin_amdgcn_global_load_lds(
        (const __attribute__((address_space(1))) void*)g,
        (__attribute__((address_space(3))) void*)l, 16, 0, 0);
}

// ---------------------------------------------------------------------------
// casts
// ---------------------------------------------------------------------------
__global__ __launch_bounds__(256)
void castf2b_kernel(const float* __restrict__ s, short* __restrict__ d, int n4) {
    int i = blockIdx.x * 256 + threadIdx.x;
    if (i >= n4) return;
    float4 v = reinterpret_cast<const float4*>(s)[i];
    union { short s[4]; int2 v; } o;
    o.s[0] = f2b(v.x); o.s[1] = f2b(v.y); o.s[2] = f2b(v.z); o.s[3] = f2b(v.w);
    reinterpret_cast<int2*>(d)[i] = o.v;
}

// W_gcn [512][256] f32 -> WgT [256][512] bf16
__global__ __launch_bounds__(256)
void wgt_kernel(const float* __restrict__ W, short* __restrict__ WT) {
    __shared__ float t[32][33];
    const int tx = threadIdx.x & 31, ty = threadIdx.x >> 5;
    const int bk = blockIdx.x * 32, bn = blockIdx.y * 32;
    #pragma unroll
    for (int i = 0; i < 4; ++i) {
        int r = ty + i * 8;
        t[r][tx] = W[(size_t)(bk + r) * DM_ + bn + tx];
    }
    __syncthreads();
    #pragma unroll
    for (int i = 0; i < 4; ++i) {
        int r = ty + i * 8;
        WT[(size_t)(bn + r) * DIN_ + bk + tx] = f2b(t[tx][r]);
    }
}

// qkv bf16 [4096][768] cols 512..767 -> VT [256][4096] (row d = head*128+dh)
__global__ __launch_bounds__(256)
void vt_kernel(const short* __restrict__ qkv, short* __restrict__ VT) {
    __shared__ short t[32][33];
    const int tx = threadIdx.x & 31, ty = threadIdx.x >> 5;
    const int bn = blockIdx.x * 32, bd = blockIdx.y * 32;
    #pragma unroll
    for (int i = 0; i < 4; ++i) {
        int r = ty + i * 8;
        t[r][tx] = qkv[(size_t)(bn + r) * 768 + 512 + bd + tx];
    }
    __syncthreads();
    #pragma unroll
    for (int i = 0; i < 4; ++i) {
        int r = ty + i * 8;
        VT[(size_t)(bd + r) * N_NODES + bn + tx] = t[tx][r];
    }
}

// ---------------------------------------------------------------------------
// bf16 MFMA GEMM: C = A[M,K] @ B^T  (B given row-major [N,K]) + bias, epi.
// 128x128 tile, 4 waves (each 64x64), BK=32, A staged in LDS (XOR-swizzled
// 16B chunks), B frags read direct from global (L2-resident weights).
// ---------------------------------------------------------------------------
template<bool BF16OUT, bool RELU, bool SPLITK>
__global__ __launch_bounds__(256)
void mgemm_kernel(const short* __restrict__ A, const short* __restrict__ B,
                  const float* __restrict__ bias,
                  float* __restrict__ Cf, short* __restrict__ Cb,
                  int M, int N, int K, int lda, int ldb, int ldc, int kchunk)
{
    __shared__ short As[128 * 32];    // 8 KB
    const int tid = threadIdx.x;
    const int lane = tid & 63, w = tid >> 6;
    const int c = lane & 15, g = lane >> 4;
    const int wm = (w >> 1) * 64, wn = (w & 1) * 64;
    const int bm = blockIdx.y * 128, bn = blockIdx.x * 128;
    int k0 = 0, kend = K;
    if (SPLITK) { k0 = blockIdx.z * kchunk; kend = min(K, k0 + kchunk); }

    const int srow = tid >> 1;               // 0..127
    const int kc0  = (tid & 1) * 2;          // 16B-chunk 0 or 2
    const short* Ag = A + (size_t)(bm + srow) * lda;

    f32x4 acc[4][4] = {};
    for (int kb = k0; kb < kend; kb += 32) {
        #pragma unroll
        for (int i = 0; i < 2; ++i) {
            int kc = kc0 + i;
            bf16x8 v = *reinterpret_cast<const bf16x8*>(Ag + kb + kc * 8);
            int kcs = kc ^ ((srow >> 1) & 3);
            *reinterpret_cast<bf16x8*>(&As[srow * 32 + kcs * 8]) = v;
        }
        __syncthreads();
        bf16x8 bf[4];
        #pragma unroll
        for (int nf = 0; nf < 4; ++nf)
            bf[nf] = *reinterpret_cast<const bf16x8*>(
                B + (size_t)(bn + wn + nf * 16 + c) * ldb + kb + g * 8);
        bf16x8 af[4];
        #pragma unroll
        for (int mf = 0; mf < 4; ++mf) {
            int row = wm + mf * 16 + c;
            int kcs = g ^ ((row >> 1) & 3);
            af[mf] = *reinterpret_cast<const bf16x8*>(&As[row * 32 + kcs * 8]);
        }
        #pragma unroll
        for (int mf = 0; mf < 4; ++mf)
            #pragma unroll
            for (int nf = 0; nf < 4; ++nf)
                acc[mf][nf] = __builtin_amdgcn_mfma_f32_16x16x32_bf16(
                    af[mf], bf[nf], acc[mf][nf], 0, 0, 0);
        __syncthreads();
    }
    #pragma unroll
    for (int mf = 0; mf < 4; ++mf) {
        const int row = bm + wm + mf * 16 + g * 4;
        #pragma unroll
        for (int nf = 0; nf < 4; ++nf) {
            const int col = bn + wn + nf * 16 + c;
            float bv = bias ? bias[col] : 0.f;
            #pragma unroll
            for (int v = 0; v < 4; ++v) {
                float val = acc[mf][nf][v];
                size_t o = (size_t)(row + v) * ldc + col;
                if (SPLITK) {
                    if (blockIdx.z == 0) val += bv;
                    atomicAdd(&Cf[o], val);
                } else {
                    val += bv;
                    if (RELU) val = fmaxf(val, 0.f);
                    if (BF16OUT) Cb[o] = f2b(val);
                    else         Cf[o] = val;
                }
            }
        }
    }
}

// ---------------------------------------------------------------------------
// Flash attention, KV-split, XCD-local, LDS-staged K/V tiles.
// 1024 blocks x 256 thr (4 waves x 16 q-rows). Split = 512 keys, tiles of 64.
// Per tile: all 4 waves cooperatively stage K[64][128] and V^T[128][64] into
// LDS via global_load_lds (16B), XOR-swizzled (byte ^= (row&7)<<4) with
// pre-swizzled global source (linear LDS dest); MFMA operands then come from
// ds_read_b128 instead of per-wave L2 loads (4x redundancy removed, no VGPR
// pressure on load pipelining).
// ---------------------------------------------------------------------------
__global__ __launch_bounds__(256)
void fattn_kernel(const short* __restrict__ qkv, const short* __restrict__ VT,
                  short* __restrict__ Opart, float* __restrict__ ml)
{
    const int bid = blockIdx.x;
    const int j = bid >> 3;
    const int pair = 2 * (bid & 7) + (j & 1);
    const int hd = pair >> 3, sp = pair & 7;
    const int qt = j >> 1;
    const int tid = threadIdx.x;
    const int w = tid >> 6, lane = tid & 63;
    const int c = lane & 15, g = lane >> 4;
    const int q0 = qt * 64 + w * 16;

    __shared__ short Klds[64 * 128];     // 16 KB, [key][dh] swizzled
    __shared__ short Vlds[128 * 64];     // 16 KB, [dh][key] swizzled
    __shared__ short Plds[4][16][88];    // per-wave, padded

    const short* Q  = qkv + (size_t)q0 * 768 + hd * 128;
    const char*  qkvC = (const char*)qkv;
    const char*  vtC  = (const char*)VT;

    bf16x8 qf[4];
    #pragma unroll
    for (int ks = 0; ks < 4; ++ks)
        qf[ks] = *reinterpret_cast<const bf16x8*>(Q + (size_t)c * 768 + ks * 32 + g * 8);

    f32x4 O[8] = {};
    float m[4]  = {-1e30f, -1e30f, -1e30f, -1e30f};
    float lsum[4] = {};                       // per-lane partial row sums
    const float C = 0.12751744f;              // log2(e)/sqrt(128)
    const int wbase = (tid & ~63) * 16;       // wave-uniform LDS chunk base

    for (int kt = sp * 8; kt < sp * 8 + 8; ++kt) {
        const int key0 = kt * 64;
        __syncthreads();                      // prev compute done before restage
        // ---- stage K tile: linear LDS dest, pre-swizzled global src ----
        #pragma unroll
        for (int i = 0; i < 4; ++i) {
            int Lr  = i * 4096 + tid * 16;
            int key = Lr >> 8;
            int lg  = (Lr & 255) ^ ((key & 7) << 4);
            const char* src = qkvC + ((size_t)(key0 + key) * 768 + 256 + hd * 128) * 2 + lg;
            gload16(src, (char*)Klds + i * 4096 + wbase);
        }
        // ---- stage V tile ----
        #pragma unroll
        for (int i = 0; i < 4; ++i) {
            int Lr = i * 4096 + tid * 16;
            int dh = Lr >> 7;
            int lg = (Lr & 127) ^ ((dh & 7) << 4);
            const char* src = vtC + (size_t)(hd * 128 + dh) * 8192 + key0 * 2 + lg;
            gload16(src, (char*)Vlds + i * 4096 + wbase);
        }
        asm volatile("s_waitcnt vmcnt(0)" ::: "memory");
        __syncthreads();                      // tile staged for all waves

        // ---- QK^T from LDS ----
        f32x4 S[4] = {};
        #pragma unroll
        for (int nf = 0; nf < 4; ++nf) {
            const int key = nf * 16 + c;
            const char* kr = (const char*)Klds + key * 256;
            const int sw = (key & 7) << 4;
            #pragma unroll
            for (int ks = 0; ks < 4; ++ks) {
                bf16x8 kf = *reinterpret_cast<const bf16x8*>(kr + ((ks * 64 + g * 16) ^ sw));
                S[nf] = __builtin_amdgcn_mfma_f32_16x16x32_bf16(qf[ks], kf, S[nf], 0, 0, 0);
            }
        }
        // ---- online softmax (log2 units, straight-line, per-lane lsum) ----
        float z[4][4];
        float mx[4];
        #pragma unroll
        for (int v = 0; v < 4; ++v) {
            #pragma unroll
            for (int nf = 0; nf < 4; ++nf) z[nf][v] = S[nf][v] * C;
            mx[v] = fmaxf(fmaxf(z[0][v], z[1][v]), fmaxf(z[2][v], z[3][v]));
        }
        #pragma unroll
        for (int off = 1; off <= 8; off <<= 1)
            #pragma unroll
            for (int v = 0; v < 4; ++v) mx[v] = fmaxf(mx[v], __shfl_xor(mx[v], off));
        #pragma unroll
        for (int v = 0; v < 4; ++v) {
            float mn = fmaxf(m[v], mx[v]);
            float scl = exp2f(m[v] - mn);
            m[v] = mn;
            lsum[v] *= scl;
            #pragma unroll
            for (int nf2 = 0; nf2 < 8; ++nf2) O[nf2][v] *= scl;
        }
        #pragma unroll
        for (int nf = 0; nf < 4; ++nf)
            #pragma unroll
            for (int v = 0; v < 4; ++v) {
                float p = exp2f(z[nf][v] - m[v]);
                lsum[v] += p;
                union { float f; unsigned u; } pu; pu.f = p;
                Plds[w][4 * g + v][nf * 16 + c] = (short)(pu.u >> 16);  // RTZ
            }
        // ---- PV from LDS ----
        bf16x8 pa[2];
        #pragma unroll
        for (int ks = 0; ks < 2; ++ks)
            pa[ks] = *reinterpret_cast<const bf16x8*>(&Plds[w][c][ks * 32 + g * 8]);
        #pragma unroll
        for (int nf2 = 0; nf2 < 8; ++nf2) {
            const int dh = nf2 * 16 + c;
            const char* vr = (const char*)Vlds + dh * 128;
            const int sw = (dh & 7) << 4;
            #pragma unroll
            for (int ks = 0; ks < 2; ++ks) {
                bf16x8 vf = *reinterpret_cast<const bf16x8*>(vr + ((ks * 64 + g * 16) ^ sw));
                O[nf2] = __builtin_amdgcn_mfma_f32_16x16x32_bf16(pa[ks], vf, O[nf2], 0, 0, 0);
            }
        }
    }
    // epilogue: one cross-lane sum reduce for lsum
    #pragma unroll
    for (int off = 1; off <= 8; off <<= 1)
        #pragma unroll
        for (int v = 0; v < 4; ++v) lsum[v] += __shfl_xor(lsum[v], off);
    const size_t pbase = ((size_t)hd * NSPLIT + sp) * N_NODES;
    #pragma unroll
    for (int v = 0; v < 4; ++v) {
        const int row = q0 + 4 * g + v;
        const size_t rowo = (pbase + row) * 128;
        #pragma unroll
        for (int nf2 = 0; nf2 < 8; ++nf2)
            Opart[rowo + nf2 * 16 + c] = f2b(O[nf2][v]);
        if (c == 0) {
            ml[(pbase + row) * 2 + 0] = m[v];       // log2 units
            ml[(pbase + row) * 2 + 1] = lsum[v];
        }
    }
}

// combine NSPLIT partials -> attnb bf16 [4096][256]; grid (4096, 2), 128 thr
__global__ __launch_bounds__(128)
void attn_combine_kernel(const short* __restrict__ Opart, const float* __restrict__ ml,
                         short* __restrict__ attnb)
{
    const int row = blockIdx.x, hd = blockIdx.y, d = threadIdx.x;
    float ms[NSPLIT], ls[NSPLIT];
    float mmax = -1e30f;
    #pragma unroll
    for (int s = 0; s < NSPLIT; ++s) {
        const size_t p = ((size_t)hd * NSPLIT + s) * N_NODES + row;
        ms[s] = ml[p * 2 + 0];
        ls[s] = ml[p * 2 + 1];
        mmax = fmaxf(mmax, ms[s]);
    }
    float lt = 0.f, acc = 0.f;
    #pragma unroll
    for (int s = 0; s < NSPLIT; ++s) {
        const float wgt = exp2f(ms[s] - mmax);
        lt += wgt * ls[s];
        const size_t p = ((size_t)hd * NSPLIT + s) * N_NODES + row;
        union { short s; unsigned short u; } b; b.s = Opart[p * 128 + d];
        union { unsigned u; float f; } cv; cv.u = ((unsigned)b.u) << 16;
        acc += wgt * cv.f;
    }
    attnb[(size_t)row * DM_ + hd * 128 + d] = f2b(acc / lt);
}

// ---------------------------------------------------------------------------
// GCN: degree, CSR build, gather-aggregate
// ---------------------------------------------------------------------------
__global__ void deg_init_kernel(float* deg, int* count) {
    int i = blockIdx.x * 256 + threadIdx.x;
    if (i < N_NODES) { deg[i] = 1.0f; count[i] = 0; }
}
__global__ void deg_accum_kernel(const int* __restrict__ dst,
                                 const float* __restrict__ w,
                                 float* deg, int* count) {
    int e = blockIdx.x * 256 + threadIdx.x;
    if (e < E_EDGES) {
        int d = dst[e];
        atomicAdd(&deg[d], w[e]);
        atomicAdd(&count[d], 1);
    }
}
__global__ void dinv_kernel(float* deg) {
    int i = blockIdx.x * 256 + threadIdx.x;
    if (i < N_NODES) deg[i] = rsqrtf(deg[i]);
}
__global__ __launch_bounds__(256)
void csr_scan_kernel(const int* __restrict__ count, int* __restrict__ start,
                     int* __restrict__ cursor) {
    __shared__ int sum[256];
    const int tid = threadIdx.x;
    const int base = tid * 16;
    int loc[16]; int s = 0;
    #pragma unroll
    for (int i = 0; i < 16; ++i) { loc[i] = count[base + i]; s += loc[i]; }
    sum[tid] = s;
    __syncthreads();
    for (int off = 1; off < 256; off <<= 1) {
        int v = (tid >= off) ? sum[tid - off] : 0;
        __syncthreads();
        sum[tid] += v;
        __syncthreads();
    }
    int run = sum[tid] - s;
    #pragma unroll
    for (int i = 0; i < 16; ++i) {
        start[base + i] = run;
        cursor[base + i] = run;
        run += loc[i];
    }
    if (tid == 255) start[N_NODES] = run;
}
__global__ void csr_fill_kernel(const int* __restrict__ src, const int* __restrict__ dst,
                                const float* __restrict__ w, const float* __restrict__ dinv,
                                int* __restrict__ cursor,
                                int* __restrict__ csr_src, float* __restrict__ csr_nrm) {
    int e = blockIdx.x * 256 + threadIdx.x;
    if (e >= E_EDGES) return;
    int s = src[e], d = dst[e];
    int pos = atomicAdd(&cursor[d], 1);
    csr_src[pos] = s;
    csr_nrm[pos] = dinv[s] * w[e] * dinv[d];
}
// one block per dst node; fuses self-loop + bias + ReLU; writes f32 + bf16
__global__ __launch_bounds__(256)
void gcn_gather_kernel(const int* __restrict__ start, const int* __restrict__ csr_src,
                       const float* __restrict__ csr_nrm, const float* __restrict__ xw,
                       const float* __restrict__ dinv, const float* __restrict__ b,
                       float* __restrict__ h, short* __restrict__ hb) {
    const int n = blockIdx.x, d = threadIdx.x;
    const int s0 = start[n], s1 = start[n + 1];
    float acc = 0.f;
    __shared__ int   ssrc[256];
    __shared__ float snrm[256];
    for (int base = s0; base < s1; base += 256) {
        const int cnt = min(256, s1 - base);
        __syncthreads();
        if (d < cnt) { ssrc[d] = csr_src[base + d]; snrm[d] = csr_nrm[base + d]; }
        __syncthreads();
        for (int j = 0; j < cnt; ++j)
            acc = fmaf(snrm[j], xw[(size_t)ssrc[j] * DM_ + d], acc);
    }
    const float di = dinv[n];
    float v = acc + di * di * xw[(size_t)n * DM_ + d] + b[d];
    v = fmaxf(v, 0.f);
    h[(size_t)n * DM_ + d] = v;
    hb[(size_t)n * DM_ + d] = f2b(v);
}

// ---------------------------------------------------------------------------
// LayerNorm(a+b); writes f32 (always) and bf16 (if outb != null)
// ---------------------------------------------------------------------------
__global__ __launch_bounds__(256)
void ln_kernel(const float* __restrict__ a, const float* __restrict__ b,
               const float* __restrict__ g, const float* __restrict__ be,
               float* __restrict__ outf, short* __restrict__ outb) {
    const int n = blockIdx.x, d = threadIdx.x;
    const size_t idx = (size_t)n * DM_ + d;
    float x = a[idx] + b[idx];
    float s = x;
    #pragma unroll
    for (int off = 32; off; off >>= 1) s += __shfl_xor(s, off);
    __shared__ float red[8];
    const int wid = d >> 6;
    if ((d & 63) == 0) red[wid] = s;
    __syncthreads();
    float mu = (red[0] + red[1] + red[2] + red[3]) * (1.f / 256.f);
    float c = x - mu;
    float q = c * c;
    #pragma unroll
    for (int off = 32; off; off >>= 1) q += __shfl_xor(q, off);
    if ((d & 63) == 0) red[4 + wid] = q;
    __syncthreads();
    float var = (red[4] + red[5] + red[6] + red[7]) * (1.f / 256.f);
    float v = c * rsqrtf(var + EPS_) * g[d] + be[d];
    outf[idx] = v;
    if (outb) outb[idx] = f2b(v);
}

// ---------------------------------------------------------------------------
extern "C" void kernel_launch(void* const* d_in, const int* in_sizes, int n_in,
                              void* d_out, int out_size, void* d_ws, size_t ws_size,
                              hipStream_t stream) {
    const float* x   = (const float*)d_in[0];
    const int*   ei  = (const int*)  d_in[1];
    const float* ew  = (const float*)d_in[2];
    const float* Wg  = (const float*)d_in[3];
    const float* bg  = (const float*)d_in[4];
    const float* inw = (const float*)d_in[5];
    const float* inb = (const float*)d_in[6];
    const float* ow  = (const float*)d_in[7];
    const float* ob  = (const float*)d_in[8];
    const float* l1w = (const float*)d_in[9];
    const float* l1b = (const float*)d_in[10];
    const float* l2w = (const float*)d_in[11];
    const float* l2b = (const float*)d_in[12];
    const float* g1  = (const float*)d_in[13];
    const float* b1  = (const float*)d_in[14];
    const float* g2  = (const float*)d_in[15];
    const float* b2  = (const float*)d_in[16];
    float* out = (float*)d_out;

    char* ws = (char*)d_ws;
    size_t off = 0;
    auto alloc = [&](size_t bytes) {
        void* p = ws + off;
        off += (bytes + 255) & ~(size_t)255;
        return p;
    };
    float* deg     = (float*)alloc((size_t)N_NODES * 4);
    int*   count   = (int*)  alloc((size_t)N_NODES * 4);
    int*   startA  = (int*)  alloc((size_t)(N_NODES + 1) * 4);
    int*   cursor  = (int*)  alloc((size_t)N_NODES * 4);
    int*   csr_src = (int*)  alloc((size_t)E_EDGES * 4);
    float* csr_nrm = (float*)alloc((size_t)E_EDGES * 4);
    short* xb    = (short*)alloc((size_t)N_NODES * DIN_ * 2);          // 4 MB
    short* WgT   = (short*)alloc((size_t)DM_ * DIN_ * 2);
    short* inwb  = (short*)alloc((size_t)768 * DM_ * 2);
    short* owb   = (short*)alloc((size_t)DM_ * DM_ * 2);
    short* l1wb  = (short*)alloc((size_t)DFF_ * DM_ * 2);
    short* l2wb  = (short*)alloc((size_t)DM_ * DFF_ * 2);
    float* xw    = (float*)alloc((size_t)N_NODES * DM_ * 4);           // 4 MB
    float* h     = (float*)alloc((size_t)N_NODES * DM_ * 4);
    short* hb    = (short*)alloc((size_t)N_NODES * DM_ * 2);
    short* qkvb  = (short*)alloc((size_t)N_NODES * 768 * 2);           // 6 MB
    short* VT    = (short*)alloc((size_t)DM_ * N_NODES * 2);           // 2 MB
    short* attnb = (short*)alloc((size_t)N_NODES * DM_ * 2);
    float* tmp   = (float*)alloc((size_t)N_NODES * DM_ * 4);
    float* h1    = (float*)alloc((size_t)N_NODES * DM_ * 4);
    short* h1b   = (short*)alloc((size_t)N_NODES * DM_ * 2);
    // shared region: {Opart bf16 + ml f32} during attention, ff1b during FFN
    size_t opart_b = (size_t)2 * NSPLIT * N_NODES * 128 * 2;           // 16.8 MB
    size_t ml_b    = (size_t)2 * NSPLIT * N_NODES * 2 * 4;             // 0.5 MB
    size_t ff1_b   = (size_t)N_NODES * DFF_ * 2;                       // 16 MB
    char*  R     = (char*)alloc(opart_b + ml_b > ff1_b ? opart_b + ml_b : ff1_b);
    short* Opart = (short*)R;
    float* ml    = (float*)(R + opart_b);
    short* ff1b  = (short*)R;
    (void)ws_size; (void)in_sizes; (void)n_in; (void)out_size;

    const int* srcI = ei;
    const int* dstI = ei + E_EDGES;

    // ---- casts ----
    castf2b_kernel<<<2048, 256, 0, stream>>>(x, xb, N_NODES * DIN_ / 4);
    wgt_kernel<<<dim3(16, 8), 256, 0, stream>>>(Wg, WgT);
    castf2b_kernel<<<192, 256, 0, stream>>>(inw, inwb, 768 * DM_ / 4);
    castf2b_kernel<<<64, 256, 0, stream>>>(ow, owb, DM_ * DM_ / 4);
    castf2b_kernel<<<512, 256, 0, stream>>>(l1w, l1wb, DFF_ * DM_ / 4);
    castf2b_kernel<<<512, 256, 0, stream>>>(l2w, l2wb, DM_ * DFF_ / 4);

    // ---- GCN ----
    deg_init_kernel<<<16, 256, 0, stream>>>(deg, count);
    deg_accum_kernel<<<E_EDGES / 256, 256, 0, stream>>>(dstI, ew, deg, count);
    dinv_kernel<<<16, 256, 0, stream>>>(deg);
    csr_scan_kernel<<<1, 256, 0, stream>>>(count, startA, cursor);
    csr_fill_kernel<<<E_EDGES / 256, 256, 0, stream>>>(srcI, dstI, ew, deg, cursor,
                                                       csr_src, csr_nrm);
    mgemm_kernel<false, false, false><<<dim3(2, 32), 256, 0, stream>>>(
        xb, WgT, nullptr, xw, nullptr, N_NODES, DM_, DIN_, DIN_, DIN_, DM_, 0);
    gcn_gather_kernel<<<N_NODES, 256, 0, stream>>>(startA, csr_src, csr_nrm, xw,
                                                   deg, bg, h, hb);

    // ---- QKV ----
    mgemm_kernel<true, false, false><<<dim3(6, 32), 256, 0, stream>>>(
        hb, inwb, inb, nullptr, qkvb, N_NODES, 768, DM_, DM_, DM_, 768, 0);
    vt_kernel<<<dim3(128, 8), 256, 0, stream>>>(qkvb, VT);

    // ---- flash attention (KV-split, XCD-local, LDS-staged) + combine ----
    fattn_kernel<<<1024, 256, 0, stream>>>(qkvb, VT, Opart, ml);
    attn_combine_kernel<<<dim3(N_NODES, 2), 128, 0, stream>>>(Opart, ml, attnb);

    // ---- out_proj + LN1 ----
    mgemm_kernel<false, false, false><<<dim3(2, 32), 256, 0, stream>>>(
        attnb, owb, ob, tmp, nullptr, N_NODES, DM_, DM_, DM_, DM_, DM_, 0);
    ln_kernel<<<N_NODES, 256, 0, stream>>>(h, tmp, g1, b1, h1, h1b);

    // ---- FFN ----
    mgemm_kernel<true, true, false><<<dim3(16, 32), 256, 0, stream>>>(
        h1b, l1wb, l1b, nullptr, ff1b, N_NODES, DFF_, DM_, DM_, DM_, DFF_, 0);
    hipMemsetAsync(tmp, 0, (size_t)N_NODES * DM_ * 4, stream);
    mgemm_kernel<false, false, true><<<dim3(2, 32, 4), 256, 0, stream>>>(
        ff1b, l2wb, l2b, tmp, nullptr, N_NODES, DM_, DFF_, DFF_, DFF_, DM_, 512);
    ln_kernel<<<N_NODES, 256, 0, stream>>>(h1, tmp, g2, b2, out, nullptr);
}

// Round 8
// 235.272 us; speedup vs baseline: 1.3353x; 1.0218x over previous
//
#include <hip/hip_runtime.h>
#include <hip/hip_bf16.h>

#define N_NODES 4096
#define E_EDGES 131072
#define DIN_    512
#define DM_     256
#define DFF_    2048
#define EPS_    1e-5f
#define NSPLIT  8

typedef __attribute__((ext_vector_type(8))) short bf16x8;   // 8 bf16 = 4 VGPR
typedef __attribute__((ext_vector_type(4))) float f32x4;

__device__ __forceinline__ short f2b(float f) {
    union { float f; unsigned u; } x; x.f = f;
    unsigned r = x.u + 0x7fff + ((x.u >> 16) & 1);   // RNE
    return (short)(r >> 16);
}

// async global->LDS, 16B per lane; lptr must be wave-uniform (HW adds lane*16)
__device__ __forceinline__ void gload16(const void* g, void* l) {
    __builtin_amdgcn_global_load_lds(
        (const __attribute__((address_space(1))) void*)g,
        (__attribute__((address_space(3))) void*)l, 16, 0, 0);
}

// ---------------------------------------------------------------------------
// casts
// ---------------------------------------------------------------------------
__global__ __launch_bounds__(256)
void castf2b_kernel(const float* __restrict__ s, short* __restrict__ d, int n4) {
    int i = blockIdx.x * 256 + threadIdx.x;
    if (i >= n4) return;
    float4 v = reinterpret_cast<const float4*>(s)[i];
    union { short s[4]; int2 v; } o;
    o.s[0] = f2b(v.x); o.s[1] = f2b(v.y); o.s[2] = f2b(v.z); o.s[3] = f2b(v.w);
    reinterpret_cast<int2*>(d)[i] = o.v;
}

// W_gcn [512][256] f32 -> WgT [256][512] bf16
__global__ __launch_bounds__(256)
void wgt_kernel(const float* __restrict__ W, short* __restrict__ WT) {
    __shared__ float t[32][33];
    const int tx = threadIdx.x & 31, ty = threadIdx.x >> 5;
    const int bk = blockIdx.x * 32, bn = blockIdx.y * 32;
    #pragma unroll
    for (int i = 0; i < 4; ++i) {
        int r = ty + i * 8;
        t[r][tx] = W[(size_t)(bk + r) * DM_ + bn + tx];
    }
    __syncthreads();
    #pragma unroll
    for (int i = 0; i < 4; ++i) {
        int r = ty + i * 8;
        WT[(size_t)(bn + r) * DIN_ + bk + tx] = f2b(t[tx][r]);
    }
}

// qkv bf16 [4096][768] cols 512..767 -> VT [256][4096] (row d = head*128+dh)
__global__ __launch_bounds__(256)
void vt_kernel(const short* __restrict__ qkv, short* __restrict__ VT) {
    __shared__ short t[32][33];
    const int tx = threadIdx.x & 31, ty = threadIdx.x >> 5;
    const int bn = blockIdx.x * 32, bd = blockIdx.y * 32;
    #pragma unroll
    for (int i = 0; i < 4; ++i) {
        int r = ty + i * 8;
        t[r][tx] = qkv[(size_t)(bn + r) * 768 + 512 + bd + tx];
    }
    __syncthreads();
    #pragma unroll
    for (int i = 0; i < 4; ++i) {
        int r = ty + i * 8;
        VT[(size_t)(bd + r) * N_NODES + bn + tx] = t[tx][r];
    }
}

// ---------------------------------------------------------------------------
// bf16 MFMA GEMM: C = A[M,K] @ B^T  (B given row-major [N,K]) + bias, epi.
// 128x128 tile, 4 waves (each 64x64), BK=32, A staged in LDS (XOR-swizzled
// 16B chunks), B frags read direct from global (L2-resident weights).
// ---------------------------------------------------------------------------
template<bool BF16OUT, bool RELU, bool SPLITK>
__global__ __launch_bounds__(256)
void mgemm_kernel(const short* __restrict__ A, const short* __restrict__ B,
                  const float* __restrict__ bias,
                  float* __restrict__ Cf, short* __restrict__ Cb,
                  int M, int N, int K, int lda, int ldb, int ldc, int kchunk)
{
    __shared__ short As[128 * 32];    // 8 KB
    const int tid = threadIdx.x;
    const int lane = tid & 63, w = tid >> 6;
    const int c = lane & 15, g = lane >> 4;
    const int wm = (w >> 1) * 64, wn = (w & 1) * 64;
    const int bm = blockIdx.y * 128, bn = blockIdx.x * 128;
    int k0 = 0, kend = K;
    if (SPLITK) { k0 = blockIdx.z * kchunk; kend = min(K, k0 + kchunk); }

    const int srow = tid >> 1;               // 0..127
    const int kc0  = (tid & 1) * 2;          // 16B-chunk 0 or 2
    const short* Ag = A + (size_t)(bm + srow) * lda;

    f32x4 acc[4][4] = {};
    for (int kb = k0; kb < kend; kb += 32) {
        #pragma unroll
        for (int i = 0; i < 2; ++i) {
            int kc = kc0 + i;
            bf16x8 v = *reinterpret_cast<const bf16x8*>(Ag + kb + kc * 8);
            int kcs = kc ^ ((srow >> 1) & 3);
            *reinterpret_cast<bf16x8*>(&As[srow * 32 + kcs * 8]) = v;
        }
        __syncthreads();
        bf16x8 bf[4];
        #pragma unroll
        for (int nf = 0; nf < 4; ++nf)
            bf[nf] = *reinterpret_cast<const bf16x8*>(
                B + (size_t)(bn + wn + nf * 16 + c) * ldb + kb + g * 8);
        bf16x8 af[4];
        #pragma unroll
        for (int mf = 0; mf < 4; ++mf) {
            int row = wm + mf * 16 + c;
            int kcs = g ^ ((row >> 1) & 3);
            af[mf] = *reinterpret_cast<const bf16x8*>(&As[row * 32 + kcs * 8]);
        }
        #pragma unroll
        for (int mf = 0; mf < 4; ++mf)
            #pragma unroll
            for (int nf = 0; nf < 4; ++nf)
                acc[mf][nf] = __builtin_amdgcn_mfma_f32_16x16x32_bf16(
                    af[mf], bf[nf], acc[mf][nf], 0, 0, 0);
        __syncthreads();
    }
    #pragma unroll
    for (int mf = 0; mf < 4; ++mf) {
        const int row = bm + wm + mf * 16 + g * 4;
        #pragma unroll
        for (int nf = 0; nf < 4; ++nf) {
            const int col = bn + wn + nf * 16 + c;
            float bv = bias ? bias[col] : 0.f;
            #pragma unroll
            for (int v = 0; v < 4; ++v) {
                float val = acc[mf][nf][v];
                size_t o = (size_t)(row + v) * ldc + col;
                if (SPLITK) {
                    if (blockIdx.z == 0) val += bv;
                    atomicAdd(&Cf[o], val);
                } else {
                    val += bv;
                    if (RELU) val = fmaxf(val, 0.f);
                    if (BF16OUT) Cb[o] = f2b(val);
                    else         Cf[o] = val;
                }
            }
        }
    }
}

// ---------------------------------------------------------------------------
// Flash attention, KV-split, XCD-local, double-buffered LDS K/V staging.
// 1024 blocks x 256 thr (4 waves x 16 q-rows). Split = 512 keys, tiles of 64.
// 2-phase pipeline: issue stage(t+1) into buf^1 BEFORE computing buf, then
// one vmcnt(0)+barrier per tile -- stage latency hides under QK+softmax+PV.
// ---------------------------------------------------------------------------
__global__ __launch_bounds__(256)
void fattn_kernel(const short* __restrict__ qkv, const short* __restrict__ VT,
                  short* __restrict__ Opart, float* __restrict__ ml)
{
    const int bid = blockIdx.x;
    const int j = bid >> 3;
    const int pair = 2 * (bid & 7) + (j & 1);
    const int hd = pair >> 3, sp = pair & 7;
    const int qt = j >> 1;
    const int tid = threadIdx.x;
    const int w = tid >> 6, lane = tid & 63;
    const int c = lane & 15, g = lane >> 4;
    const int q0 = qt * 64 + w * 16;

    __shared__ short Klds[2][64 * 128];  // 2 x 16 KB, [key][dh] swizzled
    __shared__ short Vlds[2][128 * 64];  // 2 x 16 KB, [dh][key] swizzled
    __shared__ short Plds[4][16][88];    // per-wave, padded

    const short* Q  = qkv + (size_t)q0 * 768 + hd * 128;
    const char*  qkvC = (const char*)qkv;
    const char*  vtC  = (const char*)VT;
    const int wbase = (tid & ~63) * 16;  // wave-uniform LDS chunk base

    bf16x8 qf[4];
    #pragma unroll
    for (int ks = 0; ks < 4; ++ks)
        qf[ks] = *reinterpret_cast<const bf16x8*>(Q + (size_t)c * 768 + ks * 32 + g * 8);

    auto stageKV = [&](int buf, int kt) {
        const int key0 = kt * 64;
        #pragma unroll
        for (int i = 0; i < 4; ++i) {
            int Lr  = i * 4096 + tid * 16;
            int key = Lr >> 8;
            int lg  = (Lr & 255) ^ ((key & 7) << 4);
            const char* src = qkvC + ((size_t)(key0 + key) * 768 + 256 + hd * 128) * 2 + lg;
            gload16(src, (char*)&Klds[buf][0] + i * 4096 + wbase);
        }
        #pragma unroll
        for (int i = 0; i < 4; ++i) {
            int Lr = i * 4096 + tid * 16;
            int dh = Lr >> 7;
            int lg = (Lr & 127) ^ ((dh & 7) << 4);
            const char* src = vtC + (size_t)(hd * 128 + dh) * 8192 + key0 * 2 + lg;
            gload16(src, (char*)&Vlds[buf][0] + i * 4096 + wbase);
        }
    };

    f32x4 O[8] = {};
    float m[4]  = {-1e30f, -1e30f, -1e30f, -1e30f};
    float lsum[4] = {};                       // per-lane partial row sums
    const float C = 0.12751744f;              // log2(e)/sqrt(128)

    stageKV(0, sp * 8);
    asm volatile("s_waitcnt vmcnt(0)" ::: "memory");
    __syncthreads();

    for (int t = 0; t < 8; ++t) {
        const int cur = t & 1;
        if (t < 7) stageKV(cur ^ 1, sp * 8 + t + 1);   // prefetch next tile

        // ---- QK^T from LDS ----
        f32x4 S[4] = {};
        #pragma unroll
        for (int nf = 0; nf < 4; ++nf) {
            const int key = nf * 16 + c;
            const char* kr = (const char*)&Klds[cur][0] + key * 256;
            const int sw = (key & 7) << 4;
            #pragma unroll
            for (int ks = 0; ks < 4; ++ks) {
                bf16x8 kf = *reinterpret_cast<const bf16x8*>(kr + ((ks * 64 + g * 16) ^ sw));
                S[nf] = __builtin_amdgcn_mfma_f32_16x16x32_bf16(qf[ks], kf, S[nf], 0, 0, 0);
            }
        }
        // ---- online softmax (log2 units, straight-line, per-lane lsum) ----
        float z[4][4];
        float mx[4];
        #pragma unroll
        for (int v = 0; v < 4; ++v) {
            #pragma unroll
            for (int nf = 0; nf < 4; ++nf) z[nf][v] = S[nf][v] * C;
            mx[v] = fmaxf(fmaxf(z[0][v], z[1][v]), fmaxf(z[2][v], z[3][v]));
        }
        #pragma unroll
        for (int off = 1; off <= 8; off <<= 1)
            #pragma unroll
            for (int v = 0; v < 4; ++v) mx[v] = fmaxf(mx[v], __shfl_xor(mx[v], off));
        #pragma unroll
        for (int v = 0; v < 4; ++v) {
            float mn = fmaxf(m[v], mx[v]);
            float scl = exp2f(m[v] - mn);
            m[v] = mn;
            lsum[v] *= scl;
            #pragma unroll
            for (int nf2 = 0; nf2 < 8; ++nf2) O[nf2][v] *= scl;
        }
        #pragma unroll
        for (int nf = 0; nf < 4; ++nf)
            #pragma unroll
            for (int v = 0; v < 4; ++v) {
                float p = exp2f(z[nf][v] - m[v]);
                lsum[v] += p;
                union { float f; unsigned u; } pu; pu.f = p;
                Plds[w][4 * g + v][nf * 16 + c] = (short)(pu.u >> 16);  // RTZ
            }
        // ---- PV from LDS ----
        bf16x8 pa[2];
        #pragma unroll
        for (int ks = 0; ks < 2; ++ks)
            pa[ks] = *reinterpret_cast<const bf16x8*>(&Plds[w][c][ks * 32 + g * 8]);
        #pragma unroll
        for (int nf2 = 0; nf2 < 8; ++nf2) {
            const int dh = nf2 * 16 + c;
            const char* vr = (const char*)&Vlds[cur][0] + dh * 128;
            const int sw = (dh & 7) << 4;
            #pragma unroll
            for (int ks = 0; ks < 2; ++ks) {
                bf16x8 vf = *reinterpret_cast<const bf16x8*>(vr + ((ks * 64 + g * 16) ^ sw));
                O[nf2] = __builtin_amdgcn_mfma_f32_16x16x32_bf16(pa[ks], vf, O[nf2], 0, 0, 0);
            }
        }
        asm volatile("s_waitcnt vmcnt(0)" ::: "memory");   // next tile staged
        __syncthreads();
    }
    // epilogue: one cross-lane sum reduce for lsum
    #pragma unroll
    for (int off = 1; off <= 8; off <<= 1)
        #pragma unroll
        for (int v = 0; v < 4; ++v) lsum[v] += __shfl_xor(lsum[v], off);
    const size_t pbase = ((size_t)hd * NSPLIT + sp) * N_NODES;
    #pragma unroll
    for (int v = 0; v < 4; ++v) {
        const int row = q0 + 4 * g + v;
        const size_t rowo = (pbase + row) * 128;
        #pragma unroll
        for (int nf2 = 0; nf2 < 8; ++nf2)
            Opart[rowo + nf2 * 16 + c] = f2b(O[nf2][v]);
        if (c == 0) {
            ml[(pbase + row) * 2 + 0] = m[v];       // log2 units
            ml[(pbase + row) * 2 + 1] = lsum[v];
        }
    }
}

// combine NSPLIT partials -> attnb bf16 [4096][256]; grid (4096, 2), 128 thr
__global__ __launch_bounds__(128)
void attn_combine_kernel(const short* __restrict__ Opart, const float* __restrict__ ml,
                         short* __restrict__ attnb)
{
    const int row = blockIdx.x, hd = blockIdx.y, d = threadIdx.x;
    float ms[NSPLIT], ls[NSPLIT];
    float mmax = -1e30f;
    #pragma unroll
    for (int s = 0; s < NSPLIT; ++s) {
        const size_t p = ((size_t)hd * NSPLIT + s) * N_NODES + row;
        ms[s] = ml[p * 2 + 0];
        ls[s] = ml[p * 2 + 1];
        mmax = fmaxf(mmax, ms[s]);
    }
    float lt = 0.f, acc = 0.f;
    #pragma unroll
    for (int s = 0; s < NSPLIT; ++s) {
        const float wgt = exp2f(ms[s] - mmax);
        lt += wgt * ls[s];
        const size_t p = ((size_t)hd * NSPLIT + s) * N_NODES + row;
        union { short s; unsigned short u; } b; b.s = Opart[p * 128 + d];
        union { unsigned u; float f; } cv; cv.u = ((unsigned)b.u) << 16;
        acc += wgt * cv.f;
    }
    attnb[(size_t)row * DM_ + hd * 128 + d] = f2b(acc / lt);
}

// ---------------------------------------------------------------------------
// GCN: degree, CSR build, gather-aggregate
// ---------------------------------------------------------------------------
__global__ void deg_init_kernel(float* deg, int* count) {
    int i = blockIdx.x * 256 + threadIdx.x;
    if (i < N_NODES) { deg[i] = 1.0f; count[i] = 0; }
}
__global__ void deg_accum_kernel(const int* __restrict__ dst,
                                 const float* __restrict__ w,
                                 float* deg, int* count) {
    int e = blockIdx.x * 256 + threadIdx.x;
    if (e < E_EDGES) {
        int d = dst[e];
        atomicAdd(&deg[d], w[e]);
        atomicAdd(&count[d], 1);
    }
}
__global__ void dinv_kernel(float* deg) {
    int i = blockIdx.x * 256 + threadIdx.x;
    if (i < N_NODES) deg[i] = rsqrtf(deg[i]);
}
__global__ __launch_bounds__(256)
void csr_scan_kernel(const int* __restrict__ count, int* __restrict__ start,
                     int* __restrict__ cursor) {
    __shared__ int sum[256];
    const int tid = threadIdx.x;
    const int base = tid * 16;
    int loc[16]; int s = 0;
    #pragma unroll
    for (int i = 0; i < 16; ++i) { loc[i] = count[base + i]; s += loc[i]; }
    sum[tid] = s;
    __syncthreads();
    for (int off = 1; off < 256; off <<= 1) {
        int v = (tid >= off) ? sum[tid - off] : 0;
        __syncthreads();
        sum[tid] += v;
        __syncthreads();
    }
    int run = sum[tid] - s;
    #pragma unroll
    for (int i = 0; i < 16; ++i) {
        start[base + i] = run;
        cursor[base + i] = run;
        run += loc[i];
    }
    if (tid == 255) start[N_NODES] = run;
}
__global__ void csr_fill_kernel(const int* __restrict__ src, const int* __restrict__ dst,
                                const float* __restrict__ w, const float* __restrict__ dinv,
                                int* __restrict__ cursor,
                                int* __restrict__ csr_src, float* __restrict__ csr_nrm) {
    int e = blockIdx.x * 256 + threadIdx.x;
    if (e >= E_EDGES) return;
    int s = src[e], d = dst[e];
    int pos = atomicAdd(&cursor[d], 1);
    csr_src[pos] = s;
    csr_nrm[pos] = dinv[s] * w[e] * dinv[d];
}
// one block per dst node. 4 waves split the neighbor list (every 4th edge);
// each lane owns 4 dims (float4 loads). Quarter-partials combined via LDS.
// Fuses self-loop + bias + ReLU; writes f32 + bf16.
__global__ __launch_bounds__(256)
void gcn_gather_kernel(const int* __restrict__ start, const int* __restrict__ csr_src,
                       const float* __restrict__ csr_nrm, const float* __restrict__ xw,
                       const float* __restrict__ dinv, const float* __restrict__ b,
                       float* __restrict__ h, short* __restrict__ hb) {
    const int n = blockIdx.x, tid = threadIdx.x;
    const int q = tid >> 6, lane = tid & 63;
    const int s0 = start[n], s1 = start[n + 1];
    __shared__ int    ssrc[256];
    __shared__ float  snrm[256];
    __shared__ float4 red[4][64];
    float4 acc = {0.f, 0.f, 0.f, 0.f};
    for (int base = s0; base < s1; base += 256) {
        const int cnt = min(256, s1 - base);
        __syncthreads();
        if (tid < cnt) { ssrc[tid] = csr_src[base + tid]; snrm[tid] = csr_nrm[base + tid]; }
        __syncthreads();
        for (int j = q; j < cnt; j += 4) {
            const float4 xv = *reinterpret_cast<const float4*>(
                xw + (size_t)ssrc[j] * DM_ + lane * 4);
            const float wj = snrm[j];
            acc.x = fmaf(wj, xv.x, acc.x);
            acc.y = fmaf(wj, xv.y, acc.y);
            acc.z = fmaf(wj, xv.z, acc.z);
            acc.w = fmaf(wj, xv.w, acc.w);
        }
    }
    red[q][lane] = acc;
    __syncthreads();
    if (q == 0) {
        const float4 a1 = red[1][lane], a2 = red[2][lane], a3 = red[3][lane];
        const float di = dinv[n], d2 = di * di;
        const float4 xs = *reinterpret_cast<const float4*>(xw + (size_t)n * DM_ + lane * 4);
        const float4 bv = *reinterpret_cast<const float4*>(b + lane * 4);
        float v0 = fmaxf(acc.x + a1.x + a2.x + a3.x + d2 * xs.x + bv.x, 0.f);
        float v1 = fmaxf(acc.y + a1.y + a2.y + a3.y + d2 * xs.y + bv.y, 0.f);
        float v2 = fmaxf(acc.z + a1.z + a2.z + a3.z + d2 * xs.z + bv.z, 0.f);
        float v3 = fmaxf(acc.w + a1.w + a2.w + a3.w + d2 * xs.w + bv.w, 0.f);
        const size_t o = (size_t)n * DM_ + lane * 4;
        *reinterpret_cast<float4*>(h + o) = make_float4(v0, v1, v2, v3);
        union { short s[4]; int2 v; } ob;
        ob.s[0] = f2b(v0); ob.s[1] = f2b(v1); ob.s[2] = f2b(v2); ob.s[3] = f2b(v3);
        *reinterpret_cast<int2*>(hb + o) = ob.v;
    }
}

// ---------------------------------------------------------------------------
// LayerNorm(a+b); writes f32 (always) and bf16 (if outb != null)
// ---------------------------------------------------------------------------
__global__ __launch_bounds__(256)
void ln_kernel(const float* __restrict__ a, const float* __restrict__ b,
               const float* __restrict__ g, const float* __restrict__ be,
               float* __restrict__ outf, short* __restrict__ outb) {
    const int n = blockIdx.x, d = threadIdx.x;
    const size_t idx = (size_t)n * DM_ + d;
    float x = a[idx] + b[idx];
    float s = x;
    #pragma unroll
    for (int off = 32; off; off >>= 1) s += __shfl_xor(s, off);
    __shared__ float red[8];
    const int wid = d >> 6;
    if ((d & 63) == 0) red[wid] = s;
    __syncthreads();
    float mu = (red[0] + red[1] + red[2] + red[3]) * (1.f / 256.f);
    float c = x - mu;
    float q = c * c;
    #pragma unroll
    for (int off = 32; off; off >>= 1) q += __shfl_xor(q, off);
    if ((d & 63) == 0) red[4 + wid] = q;
    __syncthreads();
    float var = (red[4] + red[5] + red[6] + red[7]) * (1.f / 256.f);
    float v = c * rsqrtf(var + EPS_) * g[d] + be[d];
    outf[idx] = v;
    if (outb) outb[idx] = f2b(v);
}

// ---------------------------------------------------------------------------
extern "C" void kernel_launch(void* const* d_in, const int* in_sizes, int n_in,
                              void* d_out, int out_size, void* d_ws, size_t ws_size,
                              hipStream_t stream) {
    const float* x   = (const float*)d_in[0];
    const int*   ei  = (const int*)  d_in[1];
    const float* ew  = (const float*)d_in[2];
    const float* Wg  = (const float*)d_in[3];
    const float* bg  = (const float*)d_in[4];
    const float* inw = (const float*)d_in[5];
    const float* inb = (const float*)d_in[6];
    const float* ow  = (const float*)d_in[7];
    const float* ob  = (const float*)d_in[8];
    const float* l1w = (const float*)d_in[9];
    const float* l1b = (const float*)d_in[10];
    const float* l2w = (const float*)d_in[11];
    const float* l2b = (const float*)d_in[12];
    const float* g1  = (const float*)d_in[13];
    const float* b1  = (const float*)d_in[14];
    const float* g2  = (const float*)d_in[15];
    const float* b2  = (const float*)d_in[16];
    float* out = (float*)d_out;

    char* ws = (char*)d_ws;
    size_t off = 0;
    auto alloc = [&](size_t bytes) {
        void* p = ws + off;
        off += (bytes + 255) & ~(size_t)255;
        return p;
    };
    float* deg     = (float*)alloc((size_t)N_NODES * 4);
    int*   count   = (int*)  alloc((size_t)N_NODES * 4);
    int*   startA  = (int*)  alloc((size_t)(N_NODES + 1) * 4);
    int*   cursor  = (int*)  alloc((size_t)N_NODES * 4);
    int*   csr_src = (int*)  alloc((size_t)E_EDGES * 4);
    float* csr_nrm = (float*)alloc((size_t)E_EDGES * 4);
    short* xb    = (short*)alloc((size_t)N_NODES * DIN_ * 2);          // 4 MB
    short* WgT   = (short*)alloc((size_t)DM_ * DIN_ * 2);
    short* inwb  = (short*)alloc((size_t)768 * DM_ * 2);
    short* owb   = (short*)alloc((size_t)DM_ * DM_ * 2);
    short* l1wb  = (short*)alloc((size_t)DFF_ * DM_ * 2);
    short* l2wb  = (short*)alloc((size_t)DM_ * DFF_ * 2);
    float* xw    = (float*)alloc((size_t)N_NODES * DM_ * 4);           // 4 MB
    float* h     = (float*)alloc((size_t)N_NODES * DM_ * 4);
    short* hb    = (short*)alloc((size_t)N_NODES * DM_ * 2);
    short* qkvb  = (short*)alloc((size_t)N_NODES * 768 * 2);           // 6 MB
    short* VT    = (short*)alloc((size_t)DM_ * N_NODES * 2);           // 2 MB
    short* attnb = (short*)alloc((size_t)N_NODES * DM_ * 2);
    float* tmp   = (float*)alloc((size_t)N_NODES * DM_ * 4);
    float* h1    = (float*)alloc((size_t)N_NODES * DM_ * 4);
    short* h1b   = (short*)alloc((size_t)N_NODES * DM_ * 2);
    // shared region: {Opart bf16 + ml f32} during attention, ff1b during FFN
    size_t opart_b = (size_t)2 * NSPLIT * N_NODES * 128 * 2;           // 16.8 MB
    size_t ml_b    = (size_t)2 * NSPLIT * N_NODES * 2 * 4;             // 0.5 MB
    size_t ff1_b   = (size_t)N_NODES * DFF_ * 2;                       // 16 MB
    char*  R     = (char*)alloc(opart_b + ml_b > ff1_b ? opart_b + ml_b : ff1_b);
    short* Opart = (short*)R;
    float* ml    = (float*)(R + opart_b);
    short* ff1b  = (short*)R;
    (void)ws_size; (void)in_sizes; (void)n_in; (void)out_size;

    const int* srcI = ei;
    const int* dstI = ei + E_EDGES;

    // ---- casts ----
    castf2b_kernel<<<2048, 256, 0, stream>>>(x, xb, N_NODES * DIN_ / 4);
    wgt_kernel<<<dim3(16, 8), 256, 0, stream>>>(Wg, WgT);
    castf2b_kernel<<<192, 256, 0, stream>>>(inw, inwb, 768 * DM_ / 4);
    castf2b_kernel<<<64, 256, 0, stream>>>(ow, owb, DM_ * DM_ / 4);
    castf2b_kernel<<<512, 256, 0, stream>>>(l1w, l1wb, DFF_ * DM_ / 4);
    castf2b_kernel<<<512, 256, 0, stream>>>(l2w, l2wb, DM_ * DFF_ / 4);

    // ---- GCN ----
    deg_init_kernel<<<16, 256, 0, stream>>>(deg, count);
    deg_accum_kernel<<<E_EDGES / 256, 256, 0, stream>>>(dstI, ew, deg, count);
    dinv_kernel<<<16, 256, 0, stream>>>(deg);
    csr_scan_kernel<<<1, 256, 0, stream>>>(count, startA, cursor);
    csr_fill_kernel<<<E_EDGES / 256, 256, 0, stream>>>(srcI, dstI, ew, deg, cursor,
                                                       csr_src, csr_nrm);
    mgemm_kernel<false, false, false><<<dim3(2, 32), 256, 0, stream>>>(
        xb, WgT, nullptr, xw, nullptr, N_NODES, DM_, DIN_, DIN_, DIN_, DM_, 0);
    gcn_gather_kernel<<<N_NODES, 256, 0, stream>>>(startA, csr_src, csr_nrm, xw,
                                                   deg, bg, h, hb);

    // ---- QKV ----
    mgemm_kernel<true, false, false><<<dim3(6, 32), 256, 0, stream>>>(
        hb, inwb, inb, nullptr, qkvb, N_NODES, 768, DM_, DM_, DM_, 768, 0);
    vt_kernel<<<dim3(128, 8), 256, 0, stream>>>(qkvb, VT);

    // ---- flash attention (KV-split, XCD-local, dbuf LDS) + combine ----
    fattn_kernel<<<1024, 256, 0, stream>>>(qkvb, VT, Opart, ml);
    attn_combine_kernel<<<dim3(N_NODES, 2), 128, 0, stream>>>(Opart, ml, attnb);

    // ---- out_proj + LN1 ----
    mgemm_kernel<false, false, false><<<dim3(2, 32), 256, 0, stream>>>(
        attnb, owb, ob, tmp, nullptr, N_NODES, DM_, DM_, DM_, DM_, DM_, 0);
    ln_kernel<<<N_NODES, 256, 0, stream>>>(h, tmp, g1, b1, h1, h1b);

    // ---- FFN ----
    mgemm_kernel<true, true, false><<<dim3(16, 32), 256, 0, stream>>>(
        h1b, l1wb, l1b, nullptr, ff1b, N_NODES, DFF_, DM_, DM_, DM_, DFF_, 0);
    hipMemsetAsync(tmp, 0, (size_t)N_NODES * DM_ * 4, stream);
    mgemm_kernel<false, false, true><<<dim3(2, 32, 4), 256, 0, stream>>>(
        ff1b, l2wb, l2b, tmp, nullptr, N_NODES, DM_, DFF_, DFF_, DFF_, DM_, 512);
    ln_kernel<<<N_NODES, 256, 0, stream>>>(h1, tmp, g2, b2, out, nullptr);
}